// Round 1
// baseline (123.843 us; speedup 1.0000x reference)
//
#include <hip/hip_runtime.h>
#include <math.h>

// Additive attention, MI355X.
// B=4, Q=K=1024, QSIZE=KSIZE=256, H=32, VDIM=256.
//
// Math restructuring:
//   tanh(fq+fk) = 1 - 2/(1 + e^{2fq} * e^{2fk})
//   -> precompute eq = e^{2 fq}, ek = e^{2 fk} once (B*(Q+K)*32 exps instead of B*Q*K*32).
//   score = sum_h w_h tanh_h + b_v = (sum_h w_h + b_v) - 2 sum_h w_h r_h, r_h = rcp(1+eq_h ek_h).
//   The additive constant cancels in softmax -> compute only s = -2 sum_h w_h r_h.
//   |s| <= 2*sum|w_h| ~ 10, so no max-subtraction needed; normalize in the epilogue.
//   Masked positions (k >= valid_len) are skipped entirely (weight 0), avg ~50% of work.

#define NB 4
#define NQ 1024
#define NK 1024
#define DQK 256
#define NH 32
#define NV 256
#define TQ 8   // q-rows per block in attn kernel

__device__ __forceinline__ float fast_rcp(float x) { return __builtin_amdgcn_rcpf(x); }

// ---------------------------------------------------------------------------
// Kernel 1: projections + elementwise exp(2x).
// One thread computes 4 h-outputs of one row (queries rows 0..4095, keys rows 4096..8191).
// grid = 8192 rows * 8 h-groups / 256 = 256 blocks.
__global__ __launch_bounds__(256) void proj_kernel(
    const float* __restrict__ queries, const float* __restrict__ keys,
    const float* __restrict__ W_q, const float* __restrict__ b_q,
    const float* __restrict__ W_k, const float* __restrict__ b_k,
    float* __restrict__ eq, float* __restrict__ ek)
{
    const int tid = blockIdx.x * 256 + threadIdx.x;
    const int h4  = (tid & 7) * 4;   // h = h4..h4+3
    const int row = tid >> 3;        // 0..8191

    const float* src; const float* W; const float* bias; float* dst; int r;
    if (row < NB * NQ) { r = row;            src = queries + (size_t)r * DQK; W = W_q; bias = b_q; dst = eq; }
    else               { r = row - NB * NQ;  src = keys    + (size_t)r * DQK; W = W_k; bias = b_k; dst = ek; }

    float4 bv4 = *(const float4*)(bias + h4);
    float a0 = bv4.x, a1 = bv4.y, a2 = bv4.z, a3 = bv4.w;
    #pragma unroll 4
    for (int i = 0; i < DQK; i += 4) {
        float4 s  = *(const float4*)(src + i);
        float4 w0 = *(const float4*)(W + (size_t)(i + 0) * NH + h4);
        float4 w1 = *(const float4*)(W + (size_t)(i + 1) * NH + h4);
        float4 w2 = *(const float4*)(W + (size_t)(i + 2) * NH + h4);
        float4 w3 = *(const float4*)(W + (size_t)(i + 3) * NH + h4);
        a0 = fmaf(s.x, w0.x, a0); a1 = fmaf(s.x, w0.y, a1); a2 = fmaf(s.x, w0.z, a2); a3 = fmaf(s.x, w0.w, a3);
        a0 = fmaf(s.y, w1.x, a0); a1 = fmaf(s.y, w1.y, a1); a2 = fmaf(s.y, w1.z, a2); a3 = fmaf(s.y, w1.w, a3);
        a0 = fmaf(s.z, w2.x, a0); a1 = fmaf(s.z, w2.y, a1); a2 = fmaf(s.z, w2.z, a2); a3 = fmaf(s.z, w2.w, a3);
        a0 = fmaf(s.w, w3.x, a0); a1 = fmaf(s.w, w3.y, a1); a2 = fmaf(s.w, w3.z, a2); a3 = fmaf(s.w, w3.w, a3);
    }
    float4 o;
    o.x = __expf(2.f * a0); o.y = __expf(2.f * a1);
    o.z = __expf(2.f * a2); o.w = __expf(2.f * a3);
    *(float4*)(dst + (size_t)r * NH + h4) = o;
}

// ---------------------------------------------------------------------------
// Kernel 2: fused scores + softmax + weighted sum over values.
// Block = 256 threads, handles (b, TQ=8 q-rows). grid = 4*128 = 512 blocks.
// Score phase: thread (qi = t&7, ks = t>>3) computes k = ks+32*i, i<32, for q=q0+qi.
// BMM phase: wave w covers k-range quarter, lane covers v = 4*lane..4*lane+3.
__global__ __launch_bounds__(256) void attn_kernel(
    const float* __restrict__ eq, const float* __restrict__ ek,
    const float* __restrict__ values, const int* __restrict__ valid_lens,
    const float* __restrict__ w_v, float* __restrict__ out)
{
    __shared__ float s_w[NK][TQ];     // 32 KB: unnormalized exp-weights [k][q]; reused for partials
    __shared__ float s_part[4][TQ];   // per-wave softmax denominators

    const int t    = threadIdx.x;
    const int b    = blockIdx.x >> 7;            // NQ/TQ = 128 blocks per batch
    const int q0   = (blockIdx.x & 127) * TQ;
    const int nvalid = valid_lens[b];            // in [1, 1024]
    const int wave = t >> 6;
    const int lane = t & 63;
    const int qi   = t & 7;
    const int ks   = t >> 3;                     // 0..31

    // w_v and eq-row in registers (tiny, L1-served broadcast loads)
    float wv[NH];
    #pragma unroll
    for (int h = 0; h < NH; h += 4) {
        float4 w4 = *(const float4*)(w_v + h);
        wv[h] = w4.x; wv[h+1] = w4.y; wv[h+2] = w4.z; wv[h+3] = w4.w;
    }
    float eqr[NH];
    const float* eqp = eq + (size_t)(b * NQ + q0 + qi) * NH;
    #pragma unroll
    for (int h = 0; h < NH; h += 4) {
        float4 e4 = *(const float4*)(eqp + h);
        eqr[h] = e4.x; eqr[h+1] = e4.y; eqr[h+2] = e4.z; eqr[h+3] = e4.w;
    }

    // ---- scores + exp, unnormalized weights straight to LDS
    const float* ekbase = ek + (size_t)b * NK * NH;
    float ssum = 0.f;
    for (int i = 0; i < 32; i++) {
        const int k = ks + 32 * i;
        float e = 0.f;
        if (k < nvalid) {
            const float* ekp = ekbase + (size_t)k * NH;
            float acc = 0.f;
            #pragma unroll
            for (int h = 0; h < NH; h += 4) {
                float4 e4 = *(const float4*)(ekp + h);
                acc = fmaf(wv[h+0], fast_rcp(1.f + eqr[h+0] * e4.x), acc);
                acc = fmaf(wv[h+1], fast_rcp(1.f + eqr[h+1] * e4.y), acc);
                acc = fmaf(wv[h+2], fast_rcp(1.f + eqr[h+2] * e4.z), acc);
                acc = fmaf(wv[h+3], fast_rcp(1.f + eqr[h+3] * e4.w), acc);
            }
            e = __expf(-2.f * acc);   // constants (sum w_h + b_v) cancel in softmax
        }
        s_w[k][qi] = e;               // (8*ks+qi) mod 32 -> 2-way bank alias = free
        ssum += e;
    }

    // ---- softmax denominator: reduce over ks (lanes stride 8 within wave, then cross-wave)
    ssum += __shfl_xor(ssum, 8, 64);
    ssum += __shfl_xor(ssum, 16, 64);
    ssum += __shfl_xor(ssum, 32, 64);
    if (lane < TQ) s_part[wave][lane] = ssum;   // lane==qi for lanes 0..7
    __syncthreads();

    // ---- bmm: wave w handles k in [w*kpw, min(nvalid,(w+1)*kpw)), lane -> v=4*lane..+3
    const int kpw  = (nvalid + 3) >> 2;
    const int kbeg = wave * kpw;
    const int kend = min(nvalid, kbeg + kpw);
    float4 acc0 = {0,0,0,0}, acc1 = {0,0,0,0}, acc2 = {0,0,0,0}, acc3 = {0,0,0,0};
    float4 acc4 = {0,0,0,0}, acc5 = {0,0,0,0}, acc6 = {0,0,0,0}, acc7 = {0,0,0,0};
    const float* vbase = values + (size_t)b * NK * NV + 4 * lane;

#define FMA4(A, W) A.x = fmaf((W), v.x, A.x); A.y = fmaf((W), v.y, A.y); \
                   A.z = fmaf((W), v.z, A.z); A.w = fmaf((W), v.w, A.w);
    #pragma unroll 2
    for (int k = kbeg; k < kend; k++) {
        float4 v  = *(const float4*)(vbase + (size_t)k * NV);
        float4 w0 = *(const float4*)(&s_w[k][0]);   // wave-uniform broadcast, 2 ds_read_b128/k
        float4 w1 = *(const float4*)(&s_w[k][4]);
        FMA4(acc0, w0.x); FMA4(acc1, w0.y); FMA4(acc2, w0.z); FMA4(acc3, w0.w);
        FMA4(acc4, w1.x); FMA4(acc5, w1.y); FMA4(acc6, w1.z); FMA4(acc7, w1.w);
    }
#undef FMA4

    __syncthreads();                 // all waves done reading s_w weights
    float* sred = &s_w[0][0];        // reuse 32 KB as [wave][q][256] partials
    {
        float4* p = (float4*)(sred + (size_t)(wave * TQ) * 256 + 4 * lane);
        p[0*64] = acc0; p[1*64] = acc1; p[2*64] = acc2; p[3*64] = acc3;
        p[4*64] = acc4; p[5*64] = acc5; p[6*64] = acc6; p[7*64] = acc7;
    }
    __syncthreads();

    // ---- final cross-wave reduction + deferred softmax normalization; thread t -> v=t
    float* obase = out + (size_t)(b * NQ + q0) * NV + t;
    #pragma unroll
    for (int q = 0; q < TQ; q++) {
        float tot = s_part[0][q] + s_part[1][q] + s_part[2][q] + s_part[3][q];
        float rs  = fast_rcp(tot);
        float r = sred[(0*TQ + q) * 256 + t] + sred[(1*TQ + q) * 256 + t]
                + sred[(2*TQ + q) * 256 + t] + sred[(3*TQ + q) * 256 + t];
        obase[(size_t)q * NV] = r * rs;
    }
}

// ---------------------------------------------------------------------------
extern "C" void kernel_launch(void* const* d_in, const int* in_sizes, int n_in,
                              void* d_out, int out_size, void* d_ws, size_t ws_size,
                              hipStream_t stream) {
    (void)in_sizes; (void)n_in; (void)out_size; (void)ws_size;
    const float* keys       = (const float*)d_in[0];
    const float* queries    = (const float*)d_in[1];
    const float* values     = (const float*)d_in[2];
    const int*   valid_lens = (const int*)d_in[3];
    const float* W_q        = (const float*)d_in[4];
    const float* b_q        = (const float*)d_in[5];
    const float* W_k        = (const float*)d_in[6];
    const float* b_k        = (const float*)d_in[7];
    const float* w_v        = (const float*)d_in[8];
    // d_in[9] = b_v: additive constant, cancels in softmax -> unused.
    float* out = (float*)d_out;

    float* eq = (float*)d_ws;                       // B*Q*32 floats
    float* ek = eq + (size_t)NB * NQ * NH;          // B*K*32 floats

    proj_kernel<<<dim3(256), dim3(256), 0, stream>>>(queries, keys, W_q, b_q, W_k, b_k, eq, ek);
    attn_kernel<<<dim3(NB * (NQ / TQ)), dim3(256), 0, stream>>>(eq, ek, values, valid_lens, w_v, out);
}

// Round 2
// 110.833 us; speedup vs baseline: 1.1174x; 1.1174x over previous
//
#include <hip/hip_runtime.h>
#include <math.h>

// Additive attention, MI355X. B=4, Q=K=1024, QSIZE=KSIZE=256, H=32, VDIM=256.
//
// Math: tanh(fq+fk) = 1 - 2/(1 + e^{2fq} e^{2fk}); precompute eq=e^{2fq}, ek=e^{2fk}.
// score = const - 2*sum_h w_h/(1+eq_h ek_h); const cancels in softmax. |s|<~10 so no
// max-subtraction; normalization deferred to epilogue. Masked k skipped.
//
// R2: latency-bound fix. attn block 256->512 (16 waves/CU resident vs 8);
// proj split dot product 4-way across lanes (1024 blocks vs 256).

#define NB 4
#define NQ 1024
#define NK 1024
#define DQK 256
#define NH 32
#define NV 256
#define TQ 8    // q-rows per attn block
#define BLK 512 // attn block size (8 waves)

__device__ __forceinline__ float fast_rcp(float x) { return __builtin_amdgcn_rcpf(x); }

// ---------------------------------------------------------------------------
// Kernel 1: projections + exp(2x). Thread = (row, 4-h group, quarter of dims).
// 8192 rows * 8 hgroups * 4 quarters = 262144 threads = 1024 blocks.
__global__ __launch_bounds__(256) void proj_kernel(
    const float* __restrict__ queries, const float* __restrict__ keys,
    const float* __restrict__ W_q, const float* __restrict__ b_q,
    const float* __restrict__ W_k, const float* __restrict__ b_k,
    float* __restrict__ eq, float* __restrict__ ek)
{
    const int tid     = blockIdx.x * 256 + threadIdx.x;
    const int row     = tid >> 5;            // 0..8191
    const int sub     = tid & 31;
    const int h4      = (sub & 7) * 4;       // h-group
    const int quarter = sub >> 3;            // 0..3 -> dims quarter*64..+63

    const float* src; const float* W; const float* bias; float* dst; int r;
    if (row < NB * NQ) { r = row;           src = queries + (size_t)r * DQK; W = W_q; bias = b_q; dst = eq; }
    else               { r = row - NB * NQ; src = keys    + (size_t)r * DQK; W = W_k; bias = b_k; dst = ek; }

    float a0 = 0.f, a1 = 0.f, a2 = 0.f, a3 = 0.f;
    if (quarter == 0) {
        float4 bv4 = *(const float4*)(bias + h4);
        a0 = bv4.x; a1 = bv4.y; a2 = bv4.z; a3 = bv4.w;
    }
    const int d0 = quarter * 64;
    #pragma unroll 4
    for (int i = d0; i < d0 + 64; i += 4) {
        float4 s  = *(const float4*)(src + i);
        float4 w0 = *(const float4*)(W + (size_t)(i + 0) * NH + h4);
        float4 w1 = *(const float4*)(W + (size_t)(i + 1) * NH + h4);
        float4 w2 = *(const float4*)(W + (size_t)(i + 2) * NH + h4);
        float4 w3 = *(const float4*)(W + (size_t)(i + 3) * NH + h4);
        a0 = fmaf(s.x, w0.x, a0); a1 = fmaf(s.x, w0.y, a1); a2 = fmaf(s.x, w0.z, a2); a3 = fmaf(s.x, w0.w, a3);
        a0 = fmaf(s.y, w1.x, a0); a1 = fmaf(s.y, w1.y, a1); a2 = fmaf(s.y, w1.z, a2); a3 = fmaf(s.y, w1.w, a3);
        a0 = fmaf(s.z, w2.x, a0); a1 = fmaf(s.z, w2.y, a1); a2 = fmaf(s.z, w2.z, a2); a3 = fmaf(s.z, w2.w, a3);
        a0 = fmaf(s.w, w3.x, a0); a1 = fmaf(s.w, w3.y, a1); a2 = fmaf(s.w, w3.z, a2); a3 = fmaf(s.w, w3.w, a3);
    }
    // reduce the 4 quarters (lanes differing in bits 3,4 of lane index)
    a0 += __shfl_xor(a0, 8, 64);  a1 += __shfl_xor(a1, 8, 64);
    a2 += __shfl_xor(a2, 8, 64);  a3 += __shfl_xor(a3, 8, 64);
    a0 += __shfl_xor(a0, 16, 64); a1 += __shfl_xor(a1, 16, 64);
    a2 += __shfl_xor(a2, 16, 64); a3 += __shfl_xor(a3, 16, 64);
    if (quarter == 0) {
        float4 o;
        o.x = __expf(2.f * a0); o.y = __expf(2.f * a1);
        o.z = __expf(2.f * a2); o.w = __expf(2.f * a3);
        *(float4*)(dst + (size_t)r * NH + h4) = o;
    }
}

// ---------------------------------------------------------------------------
// Kernel 2: fused scores + softmax + weighted sum over values.
// Block = 512 threads (8 waves), handles (b, TQ=8 q-rows). grid = 4*128 = 512.
// Score phase: thread (qi = t&7, ks = t>>3 in 0..63) covers k = ks + 64*i.
// BMM phase: wave w covers k-range eighth; lane covers v = 4*lane..4*lane+3.
__global__ __launch_bounds__(BLK) void attn_kernel(
    const float* __restrict__ eq, const float* __restrict__ ek,
    const float* __restrict__ values, const int* __restrict__ valid_lens,
    const float* __restrict__ w_v, float* __restrict__ out)
{
    __shared__ float s_w[NK][TQ];     // 32 KB: unnormalized exp-weights [k][q]; reused for partials
    __shared__ float s_part[8][TQ];   // per-wave softmax denominators

    const int t      = threadIdx.x;
    const int b      = blockIdx.x >> 7;
    const int q0     = (blockIdx.x & 127) * TQ;
    const int nvalid = valid_lens[b];           // [1, 1024]
    const int wave   = t >> 6;
    const int lane   = t & 63;
    const int qi     = t & 7;
    const int ks     = t >> 3;                  // 0..63

    float wv[NH];
    #pragma unroll
    for (int h = 0; h < NH; h += 4) {
        float4 w4 = *(const float4*)(w_v + h);
        wv[h] = w4.x; wv[h+1] = w4.y; wv[h+2] = w4.z; wv[h+3] = w4.w;
    }
    float eqr[NH];
    const float* eqp = eq + (size_t)(b * NQ + q0 + qi) * NH;
    #pragma unroll
    for (int h = 0; h < NH; h += 4) {
        float4 e4 = *(const float4*)(eqp + h);
        eqr[h] = e4.x; eqr[h+1] = e4.y; eqr[h+2] = e4.z; eqr[h+3] = e4.w;
    }

    // ---- scores + exp -> unnormalized weights in LDS
    const float* ekbase = ek + (size_t)b * NK * NH;
    const int imax = (nvalid + 63) >> 6;        // only touch k < 64*imax (covers all valid k)
    float ssum = 0.f;
    for (int i = 0; i < imax; i++) {
        const int k = ks + 64 * i;
        float e = 0.f;
        if (k < nvalid) {
            const float* ekp = ekbase + (size_t)k * NH;
            float acc = 0.f;
            #pragma unroll
            for (int h = 0; h < NH; h += 4) {
                float4 e4 = *(const float4*)(ekp + h);
                acc = fmaf(wv[h+0], fast_rcp(1.f + eqr[h+0] * e4.x), acc);
                acc = fmaf(wv[h+1], fast_rcp(1.f + eqr[h+1] * e4.y), acc);
                acc = fmaf(wv[h+2], fast_rcp(1.f + eqr[h+2] * e4.z), acc);
                acc = fmaf(wv[h+3], fast_rcp(1.f + eqr[h+3] * e4.w), acc);
            }
            e = __expf(-2.f * acc);
        }
        s_w[k][qi] = e;
        ssum += e;
    }

    // ---- per-wave softmax denominator (reduce over ks lanes: bits 3,4,5)
    ssum += __shfl_xor(ssum, 8, 64);
    ssum += __shfl_xor(ssum, 16, 64);
    ssum += __shfl_xor(ssum, 32, 64);
    if (lane < TQ) s_part[wave][lane] = ssum;
    __syncthreads();

    // ---- bmm: wave w handles k in [w*kpw, min(nvalid,(w+1)*kpw)); lane -> v=4*lane..+3
    const int kpw  = (nvalid + 7) >> 3;
    const int kbeg = wave * kpw;
    const int kend = min(nvalid, kbeg + kpw);
    float4 acc0 = {0,0,0,0}, acc1 = {0,0,0,0}, acc2 = {0,0,0,0}, acc3 = {0,0,0,0};
    float4 acc4 = {0,0,0,0}, acc5 = {0,0,0,0}, acc6 = {0,0,0,0}, acc7 = {0,0,0,0};
    const float* vbase = values + (size_t)b * NK * NV + 4 * lane;

#define FMA4(A, W) A.x = fmaf((W), v.x, A.x); A.y = fmaf((W), v.y, A.y); \
                   A.z = fmaf((W), v.z, A.z); A.w = fmaf((W), v.w, A.w);
    #pragma unroll 2
    for (int k = kbeg; k < kend; k++) {
        float4 v  = *(const float4*)(vbase + (size_t)k * NV);
        float4 w0 = *(const float4*)(&s_w[k][0]);   // wave-uniform broadcast
        float4 w1 = *(const float4*)(&s_w[k][4]);
        FMA4(acc0, w0.x); FMA4(acc1, w0.y); FMA4(acc2, w0.z); FMA4(acc3, w0.w);
        FMA4(acc4, w1.x); FMA4(acc5, w1.y); FMA4(acc6, w1.z); FMA4(acc7, w1.w);
    }
#undef FMA4

    __syncthreads();                 // all waves done reading s_w weights
    float* sred = &s_w[0][0];        // reuse 32 KB as [4 regions][q][256] partials
    float4* p = (float4*)(sred + (size_t)((wave & 3) * TQ) * 256) + lane;
    if (wave < 4) {                  // round A: waves 0..3 write their partials
        p[0*64] = acc0; p[1*64] = acc1; p[2*64] = acc2; p[3*64] = acc3;
        p[4*64] = acc4; p[5*64] = acc5; p[6*64] = acc6; p[7*64] = acc7;
    }
    __syncthreads();
    if (wave >= 4) {                 // round B: waves 4..7 accumulate in place
        float4 x;
#define ACC4(I, A) x = p[I*64]; x.x += A.x; x.y += A.y; x.z += A.z; x.w += A.w; p[I*64] = x;
        ACC4(0, acc0); ACC4(1, acc1); ACC4(2, acc2); ACC4(3, acc3);
        ACC4(4, acc4); ACC4(5, acc5); ACC4(6, acc6); ACC4(7, acc7);
#undef ACC4
    }
    __syncthreads();

    // ---- final reduction over 4 regions + deferred normalization.
    // thread t: v = t&255, handles q = (t>>8)*4 .. +3
    const int v  = t & 255;
    const int qh = (t >> 8) * 4;
    float* obase = out + (size_t)(b * NQ + q0) * NV + v;
    #pragma unroll
    for (int j = 0; j < 4; j++) {
        const int q = qh + j;
        float tot = 0.f;
        #pragma unroll
        for (int w = 0; w < 8; w++) tot += s_part[w][q];
        float rs = fast_rcp(tot);
        float r = sred[(0*TQ + q) * 256 + v] + sred[(1*TQ + q) * 256 + v]
                + sred[(2*TQ + q) * 256 + v] + sred[(3*TQ + q) * 256 + v];
        obase[(size_t)q * NV] = r * rs;
    }
}

// ---------------------------------------------------------------------------
extern "C" void kernel_launch(void* const* d_in, const int* in_sizes, int n_in,
                              void* d_out, int out_size, void* d_ws, size_t ws_size,
                              hipStream_t stream) {
    (void)in_sizes; (void)n_in; (void)out_size; (void)ws_size;
    const float* keys       = (const float*)d_in[0];
    const float* queries    = (const float*)d_in[1];
    const float* values     = (const float*)d_in[2];
    const int*   valid_lens = (const int*)d_in[3];
    const float* W_q        = (const float*)d_in[4];
    const float* b_q        = (const float*)d_in[5];
    const float* W_k        = (const float*)d_in[6];
    const float* b_k        = (const float*)d_in[7];
    const float* w_v        = (const float*)d_in[8];
    // d_in[9] = b_v: cancels in softmax.
    float* out = (float*)d_out;

    float* eq = (float*)d_ws;                       // B*Q*32 floats
    float* ek = eq + (size_t)NB * NQ * NH;          // B*K*32 floats

    proj_kernel<<<dim3(1024), dim3(256), 0, stream>>>(queries, keys, W_q, b_q, W_k, b_k, eq, ek);
    attn_kernel<<<dim3(NB * (NQ / TQ)), dim3(BLK), 0, stream>>>(eq, ek, values, valid_lens, w_v, out);
}

// Round 3
// 107.750 us; speedup vs baseline: 1.1494x; 1.0286x over previous
//
#include <hip/hip_runtime.h>
#include <math.h>

// Additive attention, MI355X. B=4, Q=K=1024, QSIZE=KSIZE=256, H=32, VDIM=256.
//
// Math: tanh(fq+fk) = 1 - 2/(1 + e^{2fq} e^{2fk}); precompute eq=e^{2fq}, ek=e^{2fk}.
// score = const - 2*sum_h w_h/u_h, u_h = 1 + eq_h ek_h; const cancels in softmax.
// Rational 2-level combine: w0/u0+w1/u1 = (w0 u1 + w1 u0)/(u0 u1) -> 1 rcp per 4 h
// (rcp is quarter-rate; this cuts score-phase issue ~35%). fminf(d,1e38) clamp
// guards the 4-way product against inf -> NaN.
//
// R3: per-wave contiguous k-range for BOTH score and BMM phases -> no barriers
// between phases (intra-wave LDS ordering suffices); waves desynchronize freely.

#define NB 4
#define NQ 1024
#define NK 1024
#define DQK 256
#define NH 32
#define NV 256
#define TQ 8    // q-rows per attn block
#define BLK 512 // attn block size (8 waves)

__device__ __forceinline__ float fast_rcp(float x) { return __builtin_amdgcn_rcpf(x); }

// ---------------------------------------------------------------------------
// Kernel 1: projections + exp(2x). Thread = (row, 4-h group, quarter of dims).
// 8192 rows * 8 hgroups * 4 quarters = 262144 threads = 1024 blocks.
__global__ __launch_bounds__(256) void proj_kernel(
    const float* __restrict__ queries, const float* __restrict__ keys,
    const float* __restrict__ W_q, const float* __restrict__ b_q,
    const float* __restrict__ W_k, const float* __restrict__ b_k,
    float* __restrict__ eq, float* __restrict__ ek)
{
    const int tid     = blockIdx.x * 256 + threadIdx.x;
    const int row     = tid >> 5;            // 0..8191
    const int sub     = tid & 31;
    const int h4      = (sub & 7) * 4;       // h-group
    const int quarter = sub >> 3;            // 0..3 -> dims quarter*64..+63

    const float* src; const float* W; const float* bias; float* dst; int r;
    if (row < NB * NQ) { r = row;           src = queries + (size_t)r * DQK; W = W_q; bias = b_q; dst = eq; }
    else               { r = row - NB * NQ; src = keys    + (size_t)r * DQK; W = W_k; bias = b_k; dst = ek; }

    float a0 = 0.f, a1 = 0.f, a2 = 0.f, a3 = 0.f;
    if (quarter == 0) {
        float4 bv4 = *(const float4*)(bias + h4);
        a0 = bv4.x; a1 = bv4.y; a2 = bv4.z; a3 = bv4.w;
    }
    const int d0 = quarter * 64;
    #pragma unroll 4
    for (int i = d0; i < d0 + 64; i += 4) {
        float4 s  = *(const float4*)(src + i);
        float4 w0 = *(const float4*)(W + (size_t)(i + 0) * NH + h4);
        float4 w1 = *(const float4*)(W + (size_t)(i + 1) * NH + h4);
        float4 w2 = *(const float4*)(W + (size_t)(i + 2) * NH + h4);
        float4 w3 = *(const float4*)(W + (size_t)(i + 3) * NH + h4);
        a0 = fmaf(s.x, w0.x, a0); a1 = fmaf(s.x, w0.y, a1); a2 = fmaf(s.x, w0.z, a2); a3 = fmaf(s.x, w0.w, a3);
        a0 = fmaf(s.y, w1.x, a0); a1 = fmaf(s.y, w1.y, a1); a2 = fmaf(s.y, w1.z, a2); a3 = fmaf(s.y, w1.w, a3);
        a0 = fmaf(s.z, w2.x, a0); a1 = fmaf(s.z, w2.y, a1); a2 = fmaf(s.z, w2.z, a2); a3 = fmaf(s.z, w2.w, a3);
        a0 = fmaf(s.w, w3.x, a0); a1 = fmaf(s.w, w3.y, a1); a2 = fmaf(s.w, w3.z, a2); a3 = fmaf(s.w, w3.w, a3);
    }
    a0 += __shfl_xor(a0, 8, 64);  a1 += __shfl_xor(a1, 8, 64);
    a2 += __shfl_xor(a2, 8, 64);  a3 += __shfl_xor(a3, 8, 64);
    a0 += __shfl_xor(a0, 16, 64); a1 += __shfl_xor(a1, 16, 64);
    a2 += __shfl_xor(a2, 16, 64); a3 += __shfl_xor(a3, 16, 64);
    if (quarter == 0) {
        float4 o;
        o.x = __expf(2.f * a0); o.y = __expf(2.f * a1);
        o.z = __expf(2.f * a2); o.w = __expf(2.f * a3);
        *(float4*)(dst + (size_t)r * NH + h4) = o;
    }
}

// ---------------------------------------------------------------------------
// Kernel 2: fused scores + softmax + weighted sum over values.
// Block = 512 threads (8 waves), handles (b, TQ=8 q-rows). grid = 4*128 = 512.
// Wave w owns k in [w*kpw, min(nvalid,(w+1)*kpw)) for BOTH phases:
//   score: lane = (qi = lane&7, kk = lane>>3) -> 8 k's per iteration
//   bmm:   lane -> v = 4*lane..4*lane+3
// No inter-wave sync until the final reduction.
__global__ __launch_bounds__(BLK, 4) void attn_kernel(
    const float* __restrict__ eq, const float* __restrict__ ek,
    const float* __restrict__ values, const int* __restrict__ valid_lens,
    const float* __restrict__ w_v, float* __restrict__ out)
{
    __shared__ float s_w[NK][TQ];     // 32 KB: unnormalized exp-weights [k][q]; reused for partials
    __shared__ float s_part[8][TQ];   // per-wave softmax denominator partials

    const int t      = threadIdx.x;
    const int b      = blockIdx.x >> 7;
    const int q0     = (blockIdx.x & 127) * TQ;
    const int nvalid = valid_lens[b];           // [1, 1024]
    const int wave   = t >> 6;
    const int lane   = t & 63;
    const int qi     = lane & 7;
    const int kk     = lane >> 3;               // 0..7

    // wave's k-range
    const int kpw  = (nvalid + 7) >> 3;
    const int kbeg = wave * kpw;
    const int kend = min(nvalid, kbeg + kpw);

    float wv[NH];
    #pragma unroll
    for (int h = 0; h < NH; h += 4) {
        float4 w4 = *(const float4*)(w_v + h);
        wv[h] = w4.x; wv[h+1] = w4.y; wv[h+2] = w4.z; wv[h+3] = w4.w;
    }
    float eqr[NH];
    const float* eqp = eq + (size_t)(b * NQ + q0 + qi) * NH;
    #pragma unroll
    for (int h = 0; h < NH; h += 4) {
        float4 e4 = *(const float4*)(eqp + h);
        eqr[h] = e4.x; eqr[h+1] = e4.y; eqr[h+2] = e4.z; eqr[h+3] = e4.w;
    }

    // ---- scores + exp -> unnormalized weights into this wave's s_w region
    const float* ekbase = ek + (size_t)b * NK * NH;
    float ssum = 0.f;
    for (int k0 = kbeg; k0 < kend; k0 += 8) {
        const int k = k0 + kk;
        if (k < kend) {
            const float* ekp = ekbase + (size_t)k * NH;
            float acc = 0.f;
            #pragma unroll
            for (int h = 0; h < NH; h += 4) {
                float4 e4 = *(const float4*)(ekp + h);
                float u0 = fmaf(eqr[h+0], e4.x, 1.f);
                float u1 = fmaf(eqr[h+1], e4.y, 1.f);
                float u2 = fmaf(eqr[h+2], e4.z, 1.f);
                float u3 = fmaf(eqr[h+3], e4.w, 1.f);
                float d01 = u0 * u1, d23 = u2 * u3;
                float n01 = fmaf(wv[h+0], u1, wv[h+1] * u0);
                float n23 = fmaf(wv[h+2], u3, wv[h+3] * u2);
                float d   = fminf(d01 * d23, 1e38f);   // inf guard
                float n   = fmaf(n01, d23, n23 * d01);
                acc = fmaf(n, fast_rcp(d), acc);
            }
            float e = __expf(-2.f * acc);
            s_w[k][qi] = e;          // (8*kk+qi)=lane mod 32 -> 2-way alias = free
            ssum += e;
        }
    }

    // per-wave softmax denominator partial (reduce over kk = lane bits 3..5)
    ssum += __shfl_xor(ssum, 8, 64);
    ssum += __shfl_xor(ssum, 16, 64);
    ssum += __shfl_xor(ssum, 32, 64);
    if (lane < TQ) s_part[wave][lane] = ssum;

    // ---- bmm over the same k-range (weights written by THIS wave: no barrier)
    float4 acc0 = {0,0,0,0}, acc1 = {0,0,0,0}, acc2 = {0,0,0,0}, acc3 = {0,0,0,0};
    float4 acc4 = {0,0,0,0}, acc5 = {0,0,0,0}, acc6 = {0,0,0,0}, acc7 = {0,0,0,0};
    const float* vbase = values + (size_t)b * NK * NV + 4 * lane;

#define FMA4(A, W) A.x = fmaf((W), v.x, A.x); A.y = fmaf((W), v.y, A.y); \
                   A.z = fmaf((W), v.z, A.z); A.w = fmaf((W), v.w, A.w);
    #pragma unroll 4
    for (int k = kbeg; k < kend; k++) {
        float4 v  = *(const float4*)(vbase + (size_t)k * NV);
        float4 w0 = *(const float4*)(&s_w[k][0]);   // wave-uniform broadcast
        float4 w1 = *(const float4*)(&s_w[k][4]);
        FMA4(acc0, w0.x); FMA4(acc1, w0.y); FMA4(acc2, w0.z); FMA4(acc3, w0.w);
        FMA4(acc4, w1.x); FMA4(acc5, w1.y); FMA4(acc6, w1.z); FMA4(acc7, w1.w);
    }
#undef FMA4

    __syncthreads();                 // everyone done with s_w as weights
    float* sred = &s_w[0][0];        // reuse 32 KB as [4 regions][q][256] partials
    float4* p = (float4*)(sred + (size_t)((wave & 3) * TQ) * 256) + lane;
    if (wave < 4) {                  // round A: waves 0..3 write their partials
        p[0*64] = acc0; p[1*64] = acc1; p[2*64] = acc2; p[3*64] = acc3;
        p[4*64] = acc4; p[5*64] = acc5; p[6*64] = acc6; p[7*64] = acc7;
    }
    __syncthreads();
    if (wave >= 4) {                 // round B: waves 4..7 accumulate in place
        float4 x;
#define ACC4(I, A) x = p[I*64]; x.x += A.x; x.y += A.y; x.z += A.z; x.w += A.w; p[I*64] = x;
        ACC4(0, acc0); ACC4(1, acc1); ACC4(2, acc2); ACC4(3, acc3);
        ACC4(4, acc4); ACC4(5, acc5); ACC4(6, acc6); ACC4(7, acc7);
#undef ACC4
    }
    __syncthreads();

    // ---- final reduction over 4 regions + deferred normalization.
    // thread t: v = t&255, handles q = (t>>8)*4 .. +3
    const int v  = t & 255;
    const int qh = (t >> 8) * 4;
    float* obase = out + (size_t)(b * NQ + q0) * NV + v;
    #pragma unroll
    for (int j = 0; j < 4; j++) {
        const int q = qh + j;
        float tot = 0.f;
        #pragma unroll
        for (int w = 0; w < 8; w++) tot += s_part[w][q];
        float rs = fast_rcp(tot);
        float r = sred[(0*TQ + q) * 256 + v] + sred[(1*TQ + q) * 256 + v]
                + sred[(2*TQ + q) * 256 + v] + sred[(3*TQ + q) * 256 + v];
        obase[(size_t)q * NV] = r * rs;
    }
}

// ---------------------------------------------------------------------------
extern "C" void kernel_launch(void* const* d_in, const int* in_sizes, int n_in,
                              void* d_out, int out_size, void* d_ws, size_t ws_size,
                              hipStream_t stream) {
    (void)in_sizes; (void)n_in; (void)out_size; (void)ws_size;
    const float* keys       = (const float*)d_in[0];
    const float* queries    = (const float*)d_in[1];
    const float* values     = (const float*)d_in[2];
    const int*   valid_lens = (const int*)d_in[3];
    const float* W_q        = (const float*)d_in[4];
    const float* b_q        = (const float*)d_in[5];
    const float* W_k        = (const float*)d_in[6];
    const float* b_k        = (const float*)d_in[7];
    const float* w_v        = (const float*)d_in[8];
    // d_in[9] = b_v: cancels in softmax.
    float* out = (float*)d_out;

    float* eq = (float*)d_ws;                       // B*Q*32 floats
    float* ek = eq + (size_t)NB * NQ * NH;          // B*K*32 floats

    proj_kernel<<<dim3(1024), dim3(256), 0, stream>>>(queries, keys, W_q, b_q, W_k, b_k, eq, ek);
    attn_kernel<<<dim3(NB * (NQ / TQ)), dim3(BLK), 0, stream>>>(eq, ek, values, valid_lens, w_v, out);
}